// Round 7
// baseline (435.523 us; speedup 1.0000x reference)
//
#include <hip/hip_runtime.h>

// Round 6: held stable (7th consecutive GPU-acquisition timeout; never run).
// Design record:
//  - Two kernels: (1) interp+softmax -> normalized fp16 weights [B,H,W,D];
//    (2) einsum GEMM (fp32 VALU; no fp32 MFMA on CDNA4) + NT stores.
//  - Byte ledger ~368 MB -> ~58 us floor @ 6.3 TB/s. Full fusion rejected
//    (saves 67 MB but +~262M interp evals / 131M exps + barriers: net loss).
//  - fp16 (not bf16) for E: [0,1] weights, rel err ~5e-4 vs ~4e-3.
//  - First-bench falsifiable predictions: FETCH+WRITE ~370 MB total,
//    k2 VGPR_Count <= ~160, hbm_pct_peak 70-80%, MfmaUtil 0.
//    Validation-fail with small absmax => fp16 E quantization (fallback fp32).

#define B 16
#define C 128
#define H 64
#define W 256
#define S 32
#define D 64

typedef _Float16 half8 __attribute__((ext_vector_type(8)));

// ---------------------------------------------------------------------------
// Kernel 1: depth scores (1D grid_sample interp along S) + softmax over H,
// fully fused: all 64 h-scores in registers, normalize in-register, store
// NORMALIZED weights as fp16 in [B,H,W,D] (d contiguous -> kernel 2 vector
// loads; wave64 store of E[b,h,w,0..63] is one contiguous 128B line).
// block 256 = 64 d-lanes x 4 w-waves; grid (W/4, B).
// ---------------------------------------------------------------------------
__global__ __launch_bounds__(256) void ppd_scores_kernel(
    const float* __restrict__ ps,    // [B,H,W,S]
    const float* __restrict__ camf,  // [B,2]
    _Float16* __restrict__ E)        // [B,H,W,D] normalized weights (ws)
{
    const int d = threadIdx.x & 63;
    const int w = (blockIdx.x << 2) + (threadIdx.x >> 6);
    const int b = blockIdx.y;

    // --- interp coefficients: depend only on (b,d) ---
    // steps[d] = 32.0 - 0.5*d (flipped arange(0.5,32.5,0.5))
    // exact reference op order for pos:
    const float fy   = camf[b * 2 + 1];
    const float step = 32.0f - 0.5f * (float)d;
    const float g    = log2f(fy / step) / 9.0f * 2.0f - 1.0f;
    const float pos  = (g + 1.0f) * 0.5f * (float)(S - 1);
    const float fi0  = floorf(pos);
    const float w1   = pos - fi0;
    const int   i0   = (int)fi0;
    const int   i1   = i0 + 1;
    const float m0   = (i0 >= 0 && i0 <= S - 1) ? 1.0f : 0.0f;  // zero padding
    const float m1   = (i1 >= 0 && i1 <= S - 1) ? 1.0f : 0.0f;
    const float c0   = (1.0f - w1) * m0;
    const float c1   = w1 * m1;
    const int idx0   = min(max(i0, 0), S - 1);
    const int idx1   = min(max(i1, 0), S - 1);

    // ps row for (b, h, w): 32 floats = one 128B line; w is wave-uniform and
    // the 64 d-lanes' gathers land in that single line -> 1 transaction/load.
    const float* __restrict__ row = ps + ((size_t)b * H * W + w) * S;

    float sc[H];
#pragma unroll
    for (int h = 0; h < H; ++h) {
        const float* r = row + (size_t)h * (W * S);
        sc[h] = r[idx0] * c0 + r[idx1] * c1;
    }

    float mx = sc[0];
#pragma unroll
    for (int h = 1; h < H; ++h) mx = fmaxf(mx, sc[h]);

    float sum = 0.0f;
#pragma unroll
    for (int h = 0; h < H; ++h) {
        sc[h] = expf(sc[h] - mx);
        sum += sc[h];
    }
    const float invZ = 1.0f / sum;

    // nontemporal: E is consumed a whole kernel later (L2 will have evicted
    // it anyway); keep k1's L2 for ps lines.
    _Float16* __restrict__ eout = E + ((size_t)b * H * W + w) * D + d;
#pragma unroll
    for (int h = 0; h < H; ++h)
        __builtin_nontemporal_store((_Float16)(sc[h] * invZ),
                                    eout + (size_t)h * (W * D));
}

// ---------------------------------------------------------------------------
// Kernel 2: out[b,c,d,w] = sum_h img[b,c,h,w] * E[b,h,w,d]  (E pre-normalized)
// Tile: Ct=16, Dt=16, Wt=64. Block 256 = 64 w-lanes x 4 c-groups (4 c each).
// img/out accesses coalesced along w; E read as 2x16B vector loads per h
// (32B/lane sectors of 128B lines; sector re-use across dt blocks is
// L2-absorbed by the XCD swizzle).
// XCD-bijective swizzle: the 32 blocks sharing (b, wtile) (8 ct x 4 dt) are
// consecutive on one XCD -> working set img 2MB + E 0.5MB < 4MB L2.
// Nontemporal out stores keep the streamed 134MB from evicting img/E in L2.
// ---------------------------------------------------------------------------
__global__ __launch_bounds__(256) void ppd_gemm_kernel(
    const float* __restrict__ img,   // [B,C,H,W]
    const _Float16* __restrict__ E,  // [B,H,W,D]
    float* __restrict__ out)         // [B,C,D,W]
{
    // nwg = 2048, divisible by 8 XCDs -> simple swizzle is bijective
    const int bid = blockIdx.x;
    const int swz = (bid & 7) * (2048 / 8) + (bid >> 3);
    // decode swz = ((b*4 + wt)*8 + ct)*4 + dt
    const int dt = swz & 3;
    const int ct = (swz >> 2) & 7;
    const int wt = (swz >> 5) & 3;
    const int b  = swz >> 7;

    const int w  = (wt << 6) + (threadIdx.x & 63);
    const int g  = threadIdx.x >> 6;   // 0..3
    const int c0 = (ct << 4) + (g << 2);
    const int d0 = dt << 4;

    const float* __restrict__ ip = img + ((size_t)b * C + c0) * (H * W) + w;
    const _Float16* __restrict__ ep = E + ((size_t)b * H * W + w) * D + d0;

    float acc[4][16];
#pragma unroll
    for (int i = 0; i < 4; ++i)
#pragma unroll
        for (int j = 0; j < 16; ++j) acc[i][j] = 0.0f;

    // unroll 2: overlap next-h loads with current-h FMAs (explicit SW pipeline)
#pragma unroll 2
    for (int h = 0; h < H; ++h) {
        float iv[4];
#pragma unroll
        for (int i = 0; i < 4; ++i)
            iv[i] = ip[((size_t)i * H + h) * W];

        const half8* evp = (const half8*)(ep + (size_t)h * (W * D));
        const half8 ev0 = evp[0];
        const half8 ev1 = evp[1];
        float pv[16];
#pragma unroll
        for (int j = 0; j < 8; ++j) {
            pv[j]     = (float)ev0[j];
            pv[j + 8] = (float)ev1[j];
        }

#pragma unroll
        for (int i = 0; i < 4; ++i)
#pragma unroll
            for (int j = 0; j < 16; ++j)
                acc[i][j] = fmaf(iv[i], pv[j], acc[i][j]);
    }

    // epilogue: store (coalesced along w), nontemporal (out never re-read)
#pragma unroll
    for (int i = 0; i < 4; ++i) {
        float* __restrict__ op = out + (((size_t)b * C + c0 + i) * D + d0) * W + w;
#pragma unroll
        for (int j = 0; j < 16; ++j)
            __builtin_nontemporal_store(acc[i][j], op + (size_t)j * W);
    }
}

extern "C" void kernel_launch(void* const* d_in, const int* in_sizes, int n_in,
                              void* d_out, int out_size, void* d_ws, size_t ws_size,
                              hipStream_t stream) {
    const float* img  = (const float*)d_in[0];  // [B,C,H,W]
    const float* ps   = (const float*)d_in[1];  // [B,H,W,S]
    const float* camf = (const float*)d_in[2];  // [B,2]
    float* out = (float*)d_out;                 // [B,C,D,W]

    _Float16* E = (_Float16*)d_ws;              // 32 MiB: [B,H,W,D] fp16

    ppd_scores_kernel<<<dim3(W / 4, B), 256, 0, stream>>>(ps, camf, E);
    ppd_gemm_kernel<<<2048, 256, 0, stream>>>(img, E, out);
}

// Round 9
// 375.818 us; speedup vs baseline: 1.1589x; 1.1589x over previous
//
#include <hip/hip_runtime.h>

// Round 8: round-7 redesign held (GPU timeout; never measured).
// Post-mortem of the one successful bench (round 7, old two-kernel design):
//   predicted k2 55us/75%HBM -> got 251us/10.7%HBM, VALU 18%: E loads were
//   64-way split transactions (lane=w but E d-contiguous). Traffic itself was
//   compulsory (~215MB) -> fix is LAYOUT, not bytes: E -> [B,HP,D,W] with
//   h-pairs packed in 4B, so k2's E loads are 256B/instr.
// k1 184us register-array pathology -> split into k1a (online stats, no
//   arrays) + k1b (recompute scores via LDS-staged ps, padded rows).
// Predictions: k2 40-50us VALU 55-70%; k1a+k1b 15-25us; total 65-85us.

#define B 16
#define C 128
#define H 64
#define W 256
#define S 32
#define D 64
#define HP 32   // H/2 h-pairs

typedef _Float16 half2v __attribute__((ext_vector_type(2)));
typedef float float4v __attribute__((ext_vector_type(4)));

// interp coefficients for depth-bin d (depend only on (fy, d)), exact
// reference op order. steps[d] = 32.0 - 0.5*d (flipped arange(0.5,32.5,0.5)).
__device__ __forceinline__ void interp_coefs(float fy, int d,
    int& idx0, int& idx1, float& c0, float& c1)
{
    const float step = 32.0f - 0.5f * (float)d;
    const float g    = log2f(fy / step) / 9.0f * 2.0f - 1.0f;
    const float pos  = (g + 1.0f) * 0.5f * (float)(S - 1);
    const float fi0  = floorf(pos);
    const float w1   = pos - fi0;
    const int   i0   = (int)fi0;
    const int   i1   = i0 + 1;
    const float m0   = (i0 >= 0 && i0 <= S - 1) ? 1.0f : 0.0f;  // zero pad
    const float m1   = (i1 >= 0 && i1 <= S - 1) ? 1.0f : 0.0f;
    c0 = (1.0f - w1) * m0;
    c1 = w1 * m1;
    idx0 = min(max(i0, 0), S - 1);
    idx1 = min(max(i1, 0), S - 1);
}

// ---------------------------------------------------------------------------
// k1a: softmax stats per (b,d,w): m = max_h score, Iz = 1/sum_h exp(s-m).
// Two passes over L1-resident ps rows (32KB/block); NO score array in regs
// (fixes the old k1's 64-float register-array pathology).
// block 256 = 64 d-lanes x 4 w; grid (W/4, B). Gathers: lane=d, idx0/idx1
// within one 128B line -> 1 txn/load. Stores: [B,D,W] lane=d scatter, but
// only 2 stores/thread (0.5M txns total — negligible).
// ---------------------------------------------------------------------------
__global__ __launch_bounds__(256) void ppd_mz_kernel(
    const float* __restrict__ ps,    // [B,H,W,S]
    const float* __restrict__ camf,  // [B,2]
    float* __restrict__ Mv,          // [B,D,W] row-max
    float* __restrict__ Iz)          // [B,D,W] 1/Z
{
    const int d = threadIdx.x & 63;
    const int w = (blockIdx.x << 2) + (threadIdx.x >> 6);
    const int b = blockIdx.y;

    int idx0, idx1; float c0, c1;
    interp_coefs(camf[b * 2 + 1], d, idx0, idx1, c0, c1);

    const float* __restrict__ row = ps + ((size_t)b * H * W + w) * S;

    float mx = -1e30f;
#pragma unroll 8
    for (int h = 0; h < H; ++h) {
        const float* r = row + (size_t)h * (W * S);
        mx = fmaxf(mx, r[idx0] * c0 + r[idx1] * c1);
    }
    float sum = 0.0f;
#pragma unroll 8
    for (int h = 0; h < H; ++h) {
        const float* r = row + (size_t)h * (W * S);
        sum += expf(r[idx0] * c0 + r[idx1] * c1 - mx);
    }
    const size_t o = ((size_t)b * D + d) * W + w;
    Mv[o] = mx;
    Iz[o] = 1.0f / sum;
}

// ---------------------------------------------------------------------------
// k1b: normalized weights E[b,hp,d,w] = (e(2hp), e(2hp+1)) packed half2.
// block = (w-tile 64, h-pair, b); 256 thr = 64 w-lanes x 4 d-groups(16 d).
// ps rows staged via LDS with 33-float padded rows: gather bank =
// (wl + idx) % 32, idx wave-uniform -> 2 lanes/bank (free). All global
// loads/stores lane=w coalesced.
// ---------------------------------------------------------------------------
__global__ __launch_bounds__(256) void ppd_weights_kernel(
    const float* __restrict__ ps,    // [B,H,W,S]
    const float* __restrict__ camf,  // [B,2]
    const float* __restrict__ Mv,    // [B,D,W]
    const float* __restrict__ Iz,    // [B,D,W]
    half2v* __restrict__ E)          // [B,HP,D,W] packed h-pairs
{
    __shared__ float lds[2 * 64 * 33];   // [2 h][64 w][32+1 pad]

    const int t  = threadIdx.x;
    const int wt = blockIdx.x;           // 0..3
    const int hp = blockIdx.y;           // 0..31
    const int b  = blockIdx.z;
    const int w0 = wt << 6;
    const int h0 = hp << 1;

    // stage 2 ps h-rows (64 w x 128B, globally linear per wave) into LDS
    {
        const int wi = t >> 2, sec = t & 3;
        const float* gsrc = ps + (((size_t)b * H + h0) * W + w0 + wi) * S + sec * 8;
        float4v a0 = *(const float4v*)(gsrc);
        float4v a1 = *(const float4v*)(gsrc + 4);
        float4v b0 = *(const float4v*)(gsrc + (size_t)W * S);
        float4v b1 = *(const float4v*)(gsrc + (size_t)W * S + 4);
        float* d0p = &lds[wi * 33 + sec * 8];
        float* d1p = d0p + 64 * 33;
#pragma unroll
        for (int k = 0; k < 4; ++k) {
            d0p[k] = a0[k]; d0p[k + 4] = a1[k];
            d1p[k] = b0[k]; d1p[k + 4] = b1[k];
        }
    }
    __syncthreads();

    const int wl = t & 63;               // lane = w
    const int w  = w0 + wl;
    const int wg = t >> 6;               // d-group
    const float fy = camf[b * 2 + 1];
    const float* r0 = &lds[wl * 33];
    const float* r1 = r0 + 64 * 33;

#pragma unroll
    for (int dd = 0; dd < 16; ++dd) {
        const int d = (wg << 4) + dd;
        int idx0, idx1; float c0, c1;
        interp_coefs(fy, d, idx0, idx1, c0, c1);
        const size_t mzo = ((size_t)b * D + d) * W + w;   // lane=w contiguous
        const float m  = Mv[mzo];
        const float iz = Iz[mzo];
        const float s0 = r0[idx0] * c0 + r0[idx1] * c1;
        const float s1 = r1[idx0] * c0 + r1[idx1] * c1;
        half2v pk;
        pk[0] = (_Float16)(expf(s0 - m) * iz);
        pk[1] = (_Float16)(expf(s1 - m) * iz);
        E[(((size_t)b * HP + hp) * D + d) * W + w] = pk;  // 256B/instr
    }
}

// ---------------------------------------------------------------------------
// k2: out[b,c,d,w] = sum_h img[b,c,h,w] * e[b,h,d,w]  (weights pre-normalized)
// Tile Ct=16 x Dt=16 x Wt=64; 256 thr = 64 w-lanes x 4 c-groups. ALL global
// accesses lane=w contiguous now (E u32 loads = 256B/instr, was 64-way split).
// No LDS. XCD-bijective swizzle keeps (b,wt)-sharing blocks L2-local
// (img 2MB + E 0.5MB < 4MB). NT stores for streamed out.
// ---------------------------------------------------------------------------
__global__ __launch_bounds__(256) void ppd_gemm_kernel(
    const float* __restrict__ img,   // [B,C,H,W]
    const half2v* __restrict__ E,    // [B,HP,D,W]
    float* __restrict__ out)         // [B,C,D,W]
{
    const int bid = blockIdx.x;
    const int swz = (bid & 7) * 256 + (bid >> 3);   // nwg=2048 % 8 == 0
    const int dt = swz & 3;
    const int ct = (swz >> 2) & 7;
    const int wt = (swz >> 5) & 3;
    const int b  = swz >> 7;

    const int w  = (wt << 6) + (threadIdx.x & 63);
    const int g  = threadIdx.x >> 6;
    const int c0 = (ct << 4) + (g << 2);
    const int d0 = dt << 4;

    const float*  __restrict__ ip = img + ((size_t)b * C + c0) * (H * W) + w;
    const half2v* __restrict__ ep = E + ((size_t)b * HP) * (D * W)
                                      + (size_t)d0 * W + w;

    float acc[4][16];
#pragma unroll
    for (int i = 0; i < 4; ++i)
#pragma unroll
        for (int j = 0; j < 16; ++j) acc[i][j] = 0.0f;

#pragma unroll 2
    for (int hp = 0; hp < HP; ++hp) {
        float iv0[4], iv1[4];
#pragma unroll
        for (int i = 0; i < 4; ++i) {
            iv0[i] = ip[((size_t)i * H + 2 * hp) * W];
            iv1[i] = ip[((size_t)i * H + 2 * hp + 1) * W];
        }
        float pv0[16], pv1[16];
#pragma unroll
        for (int j = 0; j < 16; ++j) {
            half2v e = ep[(size_t)hp * (D * W) + j * W];
            pv0[j] = (float)e[0];
            pv1[j] = (float)e[1];
        }
#pragma unroll
        for (int i = 0; i < 4; ++i)
#pragma unroll
            for (int j = 0; j < 16; ++j)
                acc[i][j] = fmaf(iv0[i], pv0[j], acc[i][j]);
#pragma unroll
        for (int i = 0; i < 4; ++i)
#pragma unroll
            for (int j = 0; j < 16; ++j)
                acc[i][j] = fmaf(iv1[i], pv1[j], acc[i][j]);
    }

#pragma unroll
    for (int i = 0; i < 4; ++i) {
        float* __restrict__ op = out + (((size_t)b * C + c0 + i) * D + d0) * W + w;
#pragma unroll
        for (int j = 0; j < 16; ++j)
            __builtin_nontemporal_store(acc[i][j], op + (size_t)j * W);
    }
}

extern "C" void kernel_launch(void* const* d_in, const int* in_sizes, int n_in,
                              void* d_out, int out_size, void* d_ws, size_t ws_size,
                              hipStream_t stream) {
    const float* img  = (const float*)d_in[0];  // [B,C,H,W]
    const float* ps   = (const float*)d_in[1];  // [B,H,W,S]
    const float* camf = (const float*)d_in[2];  // [B,2]
    float* out = (float*)d_out;                 // [B,C,D,W]

    half2v* E  = (half2v*)d_ws;                                   // 33.5 MiB
    float*  Mv = (float*)((char*)d_ws + (size_t)B * HP * D * W * sizeof(half2v));
    float*  Iz = Mv + (size_t)B * D * W;                          // +1 MiB each

    ppd_mz_kernel<<<dim3(W / 4, B), 256, 0, stream>>>(ps, camf, Mv, Iz);
    ppd_weights_kernel<<<dim3(W / 64, HP, B), 256, 0, stream>>>(ps, camf, Mv, Iz, E);
    ppd_gemm_kernel<<<2048, 256, 0, stream>>>(img, E, out);
}